// Round 9
// baseline (474.254 us; speedup 1.0000x reference)
//
#include <hip/hip_runtime.h>

#define D 64
#define BUCKET_SHIFT 8
#define ROWS_PER_BUCKET 256
#define NBUCK_MAX 1024
#define BINA_CHUNK 4096
#define BINA_THREADS 256
#define BHIST_CHUNK 16384
#define BHIST_THREADS 512

typedef unsigned int u32;
typedef unsigned long long u64;

static inline char* align16(char* p) {
    return (char*)(((uintptr_t)p + 15) & ~(uintptr_t)15);
}

// bf16x2 helpers (packed pair in one u32; low ushort = even element)
__device__ __forceinline__ float bflo(u32 p) { return __uint_as_float(p << 16); }
__device__ __forceinline__ float bfhi(u32 p) { return __uint_as_float(p & 0xFFFF0000u); }
__device__ __forceinline__ u32 pack_bf16x2(float a, float b) {
    u32 ua = __float_as_uint(a);
    u32 ub = __float_as_uint(b);
    ua = (ua + 0x7FFFu + ((ua >> 16) & 1u)) >> 16;   // RNE
    ub = (ub + 0x7FFFu + ((ub >> 16) & 1u)) >> 16;
    return ua | (ub << 16);
}

// ---------------- init ----------------

__global__ void lg_to_bf16(const float4* __restrict__ user, const float4* __restrict__ item,
                           uint2* __restrict__ dst, int user_vec4, int total_vec4) {
    int i = blockIdx.x * blockDim.x + threadIdx.x;
    if (i >= total_vec4) return;
    float4 v = (i < user_vec4) ? user[i] : item[i - user_vec4];
    dst[i] = make_uint2(pack_bf16x2(v.x, v.y), pack_bf16x2(v.z, v.w));
}

// ---------------- bucket-level histogram + scan ----------------

__global__ void lg_bhist(const int* __restrict__ rows, int* __restrict__ bcounts,
                         int nnz, int nbuck) {
    __shared__ int h[NBUCK_MAX];
    int tid = threadIdx.x;
    int bstart = blockIdx.x * BHIST_CHUNK;
    int bend = min(bstart + BHIST_CHUNK, nnz);
    for (int i = tid; i < nbuck; i += BHIST_THREADS) h[i] = 0;
    __syncthreads();
    for (int e = bstart + tid; e < bend; e += BHIST_THREADS)
        atomicAdd(&h[rows[e] >> BUCKET_SHIFT], 1);
    __syncthreads();
    for (int b = tid; b < nbuck; b += BHIST_THREADS) {
        int c = h[b];
        if (c > 0) atomicAdd(&bcounts[b], c);
    }
}

__global__ void lg_bscan(const int* __restrict__ bcounts, int* __restrict__ bucketOffs,
                         int* __restrict__ bucketCursor, int* __restrict__ offsets_end,
                         int nbuck, int nnz) {
    __shared__ int s[1024];
    int t = threadIdx.x;
    int v = (t < nbuck) ? bcounts[t] : 0;
    s[t] = v;
    __syncthreads();
    #pragma unroll
    for (int off = 1; off < 1024; off <<= 1) {
        int x = (t >= off) ? s[t - off] : 0;
        __syncthreads();
        s[t] += x;
        __syncthreads();
    }
    if (t < nbuck) {
        int excl = s[t] - v;
        bucketOffs[t] = excl;
        bucketCursor[t] = excl;
    }
    if (t == 0) {
        bucketOffs[nbuck] = nnz;
        *offsets_end = nnz;
    }
}

// ---------------- two-level bucket sort ----------------

// Pass A (LDS-staged): per 4096-edge chunk, counting-sort edges by bucket in
// LDS, then write tmp with consecutive lanes -> consecutive addresses within
// each bucket run (coalesced, L2 line-merging friendly).
__global__ void lg_binA(const int* __restrict__ rows, const int* __restrict__ cols,
                        const float* __restrict__ vals, int* __restrict__ bucketCursor,
                        u64* __restrict__ tmp, int nnz, int nbuck) {
    __shared__ int hist[NBUCK_MAX];    // counts -> local cursors
    __shared__ int delta[NBUCK_MAX];   // globalBase - localOffset per bucket
    __shared__ int s[BINA_THREADS];
    __shared__ u64 sedge[BINA_CHUNK];
    __shared__ int gdest[BINA_CHUNK];
    int tid = threadIdx.x;
    int bstart = blockIdx.x * BINA_CHUNK;
    int bend = min(bstart + BINA_CHUNK, nnz);
    int cnt = bend - bstart;

    for (int i = tid; i < nbuck; i += BINA_THREADS) hist[i] = 0;
    __syncthreads();
    for (int e = bstart + tid; e < bend; e += BINA_THREADS)
        atomicAdd(&hist[rows[e] >> BUCKET_SHIFT], 1);
    __syncthreads();

    // exclusive scan over nbuck buckets; thread t owns buckets 4t..4t+3
    int b0 = tid * 4;
    int c0 = (b0     < nbuck) ? hist[b0]     : 0;
    int c1 = (b0 + 1 < nbuck) ? hist[b0 + 1] : 0;
    int c2 = (b0 + 2 < nbuck) ? hist[b0 + 2] : 0;
    int c3 = (b0 + 3 < nbuck) ? hist[b0 + 3] : 0;
    int tsum = c0 + c1 + c2 + c3;
    s[tid] = tsum;
    __syncthreads();
    #pragma unroll
    for (int off = 1; off < BINA_THREADS; off <<= 1) {
        int x = (tid >= off) ? s[tid - off] : 0;
        __syncthreads();
        s[tid] += x;
        __syncthreads();
    }
    int run = s[tid] - tsum;
    if (b0 < nbuck) {
        int g = (c0 > 0) ? atomicAdd(&bucketCursor[b0], c0) : 0;
        delta[b0] = g - run; hist[b0] = run; run += c0;
    }
    if (b0 + 1 < nbuck) {
        int g = (c1 > 0) ? atomicAdd(&bucketCursor[b0 + 1], c1) : 0;
        delta[b0 + 1] = g - run; hist[b0 + 1] = run; run += c1;
    }
    if (b0 + 2 < nbuck) {
        int g = (c2 > 0) ? atomicAdd(&bucketCursor[b0 + 2], c2) : 0;
        delta[b0 + 2] = g - run; hist[b0 + 2] = run; run += c2;
    }
    if (b0 + 3 < nbuck) {
        int g = (c3 > 0) ? atomicAdd(&bucketCursor[b0 + 3], c3) : 0;
        delta[b0 + 3] = g - run; hist[b0 + 3] = run; run += c3;
    }
    __syncthreads();

    // scatter into LDS sorted order (rows/cols/vals re-read hit L2)
    for (int e = bstart + tid; e < bend; e += BINA_THREADS) {
        int r = rows[e];
        int b = r >> BUCKET_SHIFT;
        int p = atomicAdd(&hist[b], 1);
        u32 key = ((u32)(r & (ROWS_PER_BUCKET - 1)) << 24) | (u32)cols[e];
        sedge[p] = (u64)key | ((u64)__float_as_uint(vals[e]) << 32);
        gdest[p] = delta[b] + p;
    }
    __syncthreads();

    // linear, coalesced write-out
    for (int p = tid; p < cnt; p += BINA_THREADS)
        tmp[gdest[p]] = sedge[p];
}

// Pass B2: one block per bucket; per-row hist+scan in LDS -> emits final
// per-row CSR offsets and scatters edges into CSR order (L2-local window).
__global__ void lg_binB2(const int* __restrict__ bucketOffs, const u64* __restrict__ tmp,
                         int* __restrict__ offsets, int2* __restrict__ edges, int n) {
    __shared__ int h[ROWS_PER_BUCKET];
    __shared__ int s[ROWS_PER_BUCKET];
    __shared__ int cur[ROWS_PER_BUCKET];
    int bucket = blockIdx.x;
    int row0 = bucket << BUCKET_SHIFT;
    int tid = threadIdx.x;
    int bstart = bucketOffs[bucket];
    int bend = bucketOffs[bucket + 1];

    h[tid] = 0;
    __syncthreads();
    for (int e = bstart + tid; e < bend; e += 256)
        atomicAdd(&h[(u32)((u32)tmp[e]) >> 24], 1);
    __syncthreads();
    int v = h[tid];
    s[tid] = v;
    __syncthreads();
    #pragma unroll
    for (int off = 1; off < 256; off <<= 1) {
        int x = (tid >= off) ? s[tid - off] : 0;
        __syncthreads();
        s[tid] += x;
        __syncthreads();
    }
    int rowOff = bstart + s[tid] - v;
    int r = row0 + tid;
    if (r < n) offsets[r] = rowOff;
    cur[tid] = rowOff;
    __syncthreads();
    for (int e = bstart + tid; e < bend; e += 256) {
        u64 p = tmp[e];
        u32 key = (u32)p;
        int lr = key >> 24;
        int col = (int)(key & 0xFFFFFFu);
        int pos = atomicAdd(&cur[lr], 1);
        edges[pos] = make_int2(col, (int)(u32)(p >> 32));
    }
}

// ---------------- fallback CSR build ----------------

__global__ void lg_hist(const int* __restrict__ rows, int* __restrict__ counts, int nnz) {
    int e = blockIdx.x * blockDim.x + threadIdx.x;
    if (e >= nnz) return;
    atomicAdd(&counts[rows[e]], 1);
}

__global__ void lg_scan1(const int* __restrict__ counts, int* __restrict__ offsets,
                         int* __restrict__ cursor, int n) {
    const int T = 1024;
    int t = threadIdx.x;
    int chunk = (n + T - 1) / T;
    int start = t * chunk;
    int end = min(start + chunk, n);
    int sum = 0;
    for (int i = start; i < end; ++i) sum += counts[i];
    __shared__ int sdata[T];
    sdata[t] = sum;
    __syncthreads();
    #pragma unroll
    for (int off = 1; off < T; off <<= 1) {
        int v = (t >= off) ? sdata[t - off] : 0;
        __syncthreads();
        sdata[t] += v;
        __syncthreads();
    }
    int offset = sdata[t] - sum;
    for (int i = start; i < end; ++i) {
        int c = counts[i];
        offsets[i] = offset;
        cursor[i] = offset;
        offset += c;
    }
    if (t == T - 1) offsets[n] = sdata[T - 1];
}

__global__ void lg_fill(const int* __restrict__ rows, const int* __restrict__ cols,
                        const float* __restrict__ vals, int* __restrict__ cursor,
                        u64* __restrict__ edges, int nnz) {
    int e = blockIdx.x * blockDim.x + threadIdx.x;
    if (e >= nnz) return;
    int pos = atomicAdd(&cursor[rows[e]], 1);
    u64 packed = (u64)(u32)cols[e] | ((u64)__float_as_uint(vals[e]) << 32);
    edges[pos] = packed;
}

// ---------------- pull SpMM (bf16 gather, fp32 accumulate) ----------------

__global__ void lg_pull_bf16(const int* __restrict__ offs, const int2* __restrict__ edges,
                             const u32* __restrict__ src,
                             u32* __restrict__ nxt, int n) {
    int row = blockIdx.x * (blockDim.x >> 6) + (threadIdx.x >> 6);
    if (row >= n) return;
    int lane = threadIdx.x & 63;
    int sub = lane >> 4;
    int q = lane & 15;

    int beg = offs[row];
    int end = offs[row + 1];
    float4 acc = make_float4(0.f, 0.f, 0.f, 0.f);

    int j = beg + sub;
    for (; j + 4 < end; j += 8) {
        int2 e0 = edges[j];
        int2 e1 = edges[j + 4];
        uint2 g0 = ((const uint2*)(src + (size_t)e0.x * 32))[q];
        uint2 g1 = ((const uint2*)(src + (size_t)e1.x * 32))[q];
        float v0 = __int_as_float(e0.y);
        float v1 = __int_as_float(e1.y);
        acc.x += v0 * bflo(g0.x) + v1 * bflo(g1.x);
        acc.y += v0 * bfhi(g0.x) + v1 * bfhi(g1.x);
        acc.z += v0 * bflo(g0.y) + v1 * bflo(g1.y);
        acc.w += v0 * bfhi(g0.y) + v1 * bfhi(g1.y);
    }
    for (; j < end; j += 4) {
        int2 e = edges[j];
        uint2 g = ((const uint2*)(src + (size_t)e.x * 32))[q];
        float v = __int_as_float(e.y);
        acc.x += v * bflo(g.x);
        acc.y += v * bfhi(g.x);
        acc.z += v * bflo(g.y);
        acc.w += v * bfhi(g.y);
    }

    acc.x += __shfl_xor(acc.x, 16, 64); acc.x += __shfl_xor(acc.x, 32, 64);
    acc.y += __shfl_xor(acc.y, 16, 64); acc.y += __shfl_xor(acc.y, 32, 64);
    acc.z += __shfl_xor(acc.z, 16, 64); acc.z += __shfl_xor(acc.z, 32, 64);
    acc.w += __shfl_xor(acc.w, 16, 64); acc.w += __shfl_xor(acc.w, 32, 64);

    float ss = acc.x * acc.x + acc.y * acc.y + acc.z * acc.z + acc.w * acc.w;
    #pragma unroll
    for (int off = 1; off < 16; off <<= 1) ss += __shfl_xor(ss, off, 64);
    float inv = 1.0f / fmaxf(sqrtf(ss), 1e-12f);

    if (sub == 0) {
        uint2 o = make_uint2(pack_bf16x2(acc.x * inv, acc.y * inv),
                             pack_bf16x2(acc.z * inv, acc.w * inv));
        ((uint2*)(nxt + (size_t)row * 32))[q] = o;
    }
}

// Final pull: layer-3 propagation fused with the 4-layer mean.
// out[row] = (e0_fp32 + e1 + e2 + normalize(gather)) * 0.25
__global__ void lg_pull_final(const int* __restrict__ offs, const int2* __restrict__ edges,
                              const u32* __restrict__ src,      // e2 table (gather source)
                              const float4* __restrict__ user, const float4* __restrict__ item,
                              int nU,
                              const u32* __restrict__ e1b,
                              float4* __restrict__ out, int n) {
    int row = blockIdx.x * (blockDim.x >> 6) + (threadIdx.x >> 6);
    if (row >= n) return;
    int lane = threadIdx.x & 63;
    int sub = lane >> 4;
    int q = lane & 15;

    int beg = offs[row];
    int end = offs[row + 1];
    float4 acc = make_float4(0.f, 0.f, 0.f, 0.f);

    int j = beg + sub;
    for (; j + 4 < end; j += 8) {
        int2 e0 = edges[j];
        int2 e1 = edges[j + 4];
        uint2 g0 = ((const uint2*)(src + (size_t)e0.x * 32))[q];
        uint2 g1 = ((const uint2*)(src + (size_t)e1.x * 32))[q];
        float v0 = __int_as_float(e0.y);
        float v1 = __int_as_float(e1.y);
        acc.x += v0 * bflo(g0.x) + v1 * bflo(g1.x);
        acc.y += v0 * bfhi(g0.x) + v1 * bfhi(g1.x);
        acc.z += v0 * bflo(g0.y) + v1 * bflo(g1.y);
        acc.w += v0 * bfhi(g0.y) + v1 * bfhi(g1.y);
    }
    for (; j < end; j += 4) {
        int2 e = edges[j];
        uint2 g = ((const uint2*)(src + (size_t)e.x * 32))[q];
        float v = __int_as_float(e.y);
        acc.x += v * bflo(g.x);
        acc.y += v * bfhi(g.x);
        acc.z += v * bflo(g.y);
        acc.w += v * bfhi(g.y);
    }

    acc.x += __shfl_xor(acc.x, 16, 64); acc.x += __shfl_xor(acc.x, 32, 64);
    acc.y += __shfl_xor(acc.y, 16, 64); acc.y += __shfl_xor(acc.y, 32, 64);
    acc.z += __shfl_xor(acc.z, 16, 64); acc.z += __shfl_xor(acc.z, 32, 64);
    acc.w += __shfl_xor(acc.w, 16, 64); acc.w += __shfl_xor(acc.w, 32, 64);

    float ss = acc.x * acc.x + acc.y * acc.y + acc.z * acc.z + acc.w * acc.w;
    #pragma unroll
    for (int off = 1; off < 16; off <<= 1) ss += __shfl_xor(ss, off, 64);
    float inv = 1.0f / fmaxf(sqrtf(ss), 1e-12f);

    if (sub == 0) {
        float4 a = (row < nU) ? user[row * 16 + q] : item[(row - nU) * 16 + q];
        uint2 b1 = ((const uint2*)(e1b + (size_t)row * 32))[q];
        uint2 b2 = ((const uint2*)(src + (size_t)row * 32))[q];
        float4 r;
        r.x = (a.x + bflo(b1.x) + bflo(b2.x) + acc.x * inv) * 0.25f;
        r.y = (a.y + bfhi(b1.x) + bfhi(b2.x) + acc.y * inv) * 0.25f;
        r.z = (a.z + bflo(b1.y) + bflo(b2.y) + acc.z * inv) * 0.25f;
        r.w = (a.w + bfhi(b1.y) + bfhi(b2.y) + acc.w * inv) * 0.25f;
        out[(size_t)row * 16 + q] = r;
    }
}

// ---------------- fallback (atomic-scatter fp32 path) ----------------

__global__ void lg_init(const float4* __restrict__ user, const float4* __restrict__ item,
                        float4* __restrict__ cur, float4* __restrict__ sum,
                        int user_vec4, int total_vec4) {
    int i = blockIdx.x * blockDim.x + threadIdx.x;
    if (i >= total_vec4) return;
    float4 v = (i < user_vec4) ? user[i] : item[i - user_vec4];
    cur[i] = v;
    sum[i] = v;
}

__global__ void lg_scatter(const int* __restrict__ rows, const int* __restrict__ cols,
                           const float* __restrict__ vals,
                           const float* __restrict__ cur, float* __restrict__ next,
                           int nnz) {
    int gid = blockIdx.x * blockDim.x + threadIdx.x;
    int e = gid >> 6;
    int d = gid & 63;
    if (e >= nnz) return;
    atomicAdd(&next[rows[e] * D + d], vals[e] * cur[cols[e] * D + d]);
}

__global__ void lg_norm_acc(float* __restrict__ emb, float* __restrict__ sum, int n) {
    int row = blockIdx.x * (blockDim.x >> 6) + (threadIdx.x >> 6);
    int d = threadIdx.x & 63;
    if (row >= n) return;
    int idx = row * D + d;
    float v = emb[idx];
    float ss = v * v;
    #pragma unroll
    for (int off = 32; off > 0; off >>= 1) ss += __shfl_xor(ss, off, 64);
    float out = v / fmaxf(sqrtf(ss), 1e-12f);
    emb[idx] = out;
    sum[idx] += out;
}

__global__ void lg_final(float4* __restrict__ out, int n4) {
    int i = blockIdx.x * blockDim.x + threadIdx.x;
    if (i >= n4) return;
    float4 s = out[i];
    out[i] = make_float4(s.x * 0.25f, s.y * 0.25f, s.z * 0.25f, s.w * 0.25f);
}

// ---------------- launch ----------------

extern "C" void kernel_launch(void* const* d_in, const int* in_sizes, int n_in,
                              void* d_out, int out_size, void* d_ws, size_t ws_size,
                              hipStream_t stream) {
    const float* user = (const float*)d_in[0];
    const float* item = (const float*)d_in[1];
    const float* vals = (const float*)d_in[2];
    const int*   rows = (const int*)d_in[3];
    const int*   cols = (const int*)d_in[4];

    const int nU  = in_sizes[0] / D;
    const int nI  = in_sizes[1] / D;
    const int N   = nU + nI;
    const int nnz = in_sizes[2];

    const size_t embElems = (size_t)N * D;
    const size_t embU32   = (size_t)N * 32;
    const int total4 = (int)(embElems / 4);
    float* out = (float*)d_out;

    // ws layout
    char* p = (char*)d_ws;
    u32* t0  = (u32*)p;           p = align16(p + embU32 * sizeof(u32));
    u32* e1b = (u32*)p;           p = align16(p + embU32 * sizeof(u32));
    u32* e2b = (u32*)p;           p = align16(p + embU32 * sizeof(u32));
    int* counts   = (int*)p;      p = align16(p + (size_t)N * sizeof(int));     // fallback only
    int* offsets  = (int*)p;      p = align16(p + (size_t)(N + 1) * sizeof(int));
    int* cursor   = (int*)p;      p = align16(p + (size_t)N * sizeof(int));     // fallback only
    int* bcounts  = (int*)p;      p = align16(p + NBUCK_MAX * sizeof(int));
    int* bucketOffs = (int*)p;    p = align16(p + (NBUCK_MAX + 1) * sizeof(int));
    int* bucketCursor = (int*)p;  p = align16(p + NBUCK_MAX * sizeof(int));
    u64* edges    = (u64*)p;      p = align16(p + (size_t)nnz * sizeof(u64));
    u64* tmp      = (u64*)p;      p = align16(p + (size_t)nnz * sizeof(u64));
    size_t needBytes = (size_t)(p - (char*)d_ws);
    size_t needNoTmp = needBytes - ((size_t)nnz * sizeof(u64) + 16);

    const int nbuck = (N + ROWS_PER_BUCKET - 1) / ROWS_PER_BUCKET;

    if (ws_size >= needNoTmp) {
        lg_to_bf16<<<(total4 + 255) / 256, 256, 0, stream>>>(
            (const float4*)user, (const float4*)item, (uint2*)t0, nU * D / 4, total4);

        if (nbuck <= NBUCK_MAX && ws_size >= needBytes) {
            hipMemsetAsync(bcounts, 0, (size_t)nbuck * sizeof(int), stream);
            int hb = (nnz + BHIST_CHUNK - 1) / BHIST_CHUNK;
            lg_bhist<<<hb, BHIST_THREADS, 0, stream>>>(rows, bcounts, nnz, nbuck);
            lg_bscan<<<1, 1024, 0, stream>>>(bcounts, bucketOffs, bucketCursor,
                                             offsets + N, nbuck, nnz);
            int ab = (nnz + BINA_CHUNK - 1) / BINA_CHUNK;
            lg_binA<<<ab, BINA_THREADS, 0, stream>>>(rows, cols, vals, bucketCursor,
                                                     tmp, nnz, nbuck);
            lg_binB2<<<nbuck, 256, 0, stream>>>(bucketOffs, tmp, offsets, (int2*)edges, N);
        } else {
            hipMemsetAsync(counts, 0, (size_t)N * sizeof(int), stream);
            int eb = (nnz + 255) / 256;
            lg_hist<<<eb, 256, 0, stream>>>(rows, counts, nnz);
            lg_scan1<<<1, 1024, 0, stream>>>(counts, offsets, cursor, N);
            lg_fill<<<eb, 256, 0, stream>>>(rows, cols, vals, cursor, edges, nnz);
        }

        // ---- layers 1,2 bf16; layer 3 fused with mean ----
        int rb = (N + 3) / 4;
        lg_pull_bf16<<<rb, 256, 0, stream>>>(offsets, (const int2*)edges, t0,  e1b, N);
        lg_pull_bf16<<<rb, 256, 0, stream>>>(offsets, (const int2*)edges, e1b, e2b, N);
        lg_pull_final<<<rb, 256, 0, stream>>>(offsets, (const int2*)edges, e2b,
                                              (const float4*)user, (const float4*)item, nU,
                                              e1b, (float4*)out, N);
    } else {
        // fallback: fp32 atomic scatter
        float* buf0 = (float*)t0;
        float* buf1 = buf0 + embElems;
        float* sum  = out;
        lg_init<<<(total4 + 255) / 256, 256, 0, stream>>>(
            (const float4*)user, (const float4*)item,
            (float4*)buf0, (float4*)sum, nU * D / 4, total4);
        float* cur = buf0;
        float* nxt = buf1;
        for (int layer = 0; layer < 3; ++layer) {
            hipMemsetAsync(nxt, 0, embElems * sizeof(float), stream);
            int totThreads = nnz * 64;
            int blocks = (totThreads + 255) / 256;
            lg_scatter<<<blocks, 256, 0, stream>>>(rows, cols, vals, cur, nxt, nnz);
            lg_norm_acc<<<(N + 3) / 4, 256, 0, stream>>>(nxt, sum, N);
            float* t = cur; cur = nxt; nxt = t;
        }
        lg_final<<<(total4 + 255) / 256, 256, 0, stream>>>((float4*)sum, total4);
    }
}

// Round 10
// 426.812 us; speedup vs baseline: 1.1112x; 1.1112x over previous
//
#include <hip/hip_runtime.h>

#define D 64
#define BUCKET_SHIFT 8
#define ROWS_PER_BUCKET 256
#define NBUCK_MAX 1024
#define BINA_CHUNK 8192
#define BINA_THREADS 512
#define BHIST_CHUNK 16384
#define BHIST_THREADS 512

typedef unsigned int u32;
typedef unsigned long long u64;

static inline char* align16(char* p) {
    return (char*)(((uintptr_t)p + 15) & ~(uintptr_t)15);
}

// bf16x2 helpers (packed pair in one u32; low ushort = even element)
__device__ __forceinline__ float bflo(u32 p) { return __uint_as_float(p << 16); }
__device__ __forceinline__ float bfhi(u32 p) { return __uint_as_float(p & 0xFFFF0000u); }
__device__ __forceinline__ u32 pack_bf16x2(float a, float b) {
    u32 ua = __float_as_uint(a);
    u32 ub = __float_as_uint(b);
    ua = (ua + 0x7FFFu + ((ua >> 16) & 1u)) >> 16;   // RNE
    ub = (ub + 0x7FFFu + ((ub >> 16) & 1u)) >> 16;
    return ua | (ub << 16);
}

// ---------------- init ----------------

__global__ void lg_to_bf16(const float4* __restrict__ user, const float4* __restrict__ item,
                           uint2* __restrict__ dst, int user_vec4, int total_vec4) {
    int i = blockIdx.x * blockDim.x + threadIdx.x;
    if (i >= total_vec4) return;
    float4 v = (i < user_vec4) ? user[i] : item[i - user_vec4];
    dst[i] = make_uint2(pack_bf16x2(v.x, v.y), pack_bf16x2(v.z, v.w));
}

// ---------------- bucket-level histogram + scan ----------------

__global__ void lg_bhist(const int* __restrict__ rows, int* __restrict__ bcounts,
                         int nnz, int nbuck) {
    __shared__ int h[NBUCK_MAX];
    int tid = threadIdx.x;
    int bstart = blockIdx.x * BHIST_CHUNK;
    int bend = min(bstart + BHIST_CHUNK, nnz);
    for (int i = tid; i < nbuck; i += BHIST_THREADS) h[i] = 0;
    __syncthreads();
    for (int e = bstart + tid; e < bend; e += BHIST_THREADS)
        atomicAdd(&h[rows[e] >> BUCKET_SHIFT], 1);
    __syncthreads();
    for (int b = tid; b < nbuck; b += BHIST_THREADS) {
        int c = h[b];
        if (c > 0) atomicAdd(&bcounts[b], c);
    }
}

__global__ void lg_bscan(const int* __restrict__ bcounts, int* __restrict__ bucketOffs,
                         int* __restrict__ bucketCursor, int* __restrict__ offsets_end,
                         int nbuck, int nnz) {
    __shared__ int s[1024];
    int t = threadIdx.x;
    int v = (t < nbuck) ? bcounts[t] : 0;
    s[t] = v;
    __syncthreads();
    #pragma unroll
    for (int off = 1; off < 1024; off <<= 1) {
        int x = (t >= off) ? s[t - off] : 0;
        __syncthreads();
        s[t] += x;
        __syncthreads();
    }
    if (t < nbuck) {
        int excl = s[t] - v;
        bucketOffs[t] = excl;
        bucketCursor[t] = excl;
    }
    if (t == 0) {
        bucketOffs[nbuck] = nnz;
        *offsets_end = nnz;
    }
}

// ---------------- two-level bucket sort ----------------

// Pass A (R8 form): LDS hist -> one global atomic per (block,bucket) to
// reserve runs -> direct global scatter. Same-block per-bucket runs are
// contiguous and merge to full lines in the writing XCD's L2. High
// occupancy (8 KB LDS) hides the scatter latency — this beat the
// LDS-staged variant (R9: 58 KB LDS, 1.15M bank conflicts, 16% occ).
__global__ void lg_binA(const int* __restrict__ rows, const int* __restrict__ cols,
                        const float* __restrict__ vals, int* __restrict__ bucketCursor,
                        u64* __restrict__ tmp, int nnz, int nbuck) {
    __shared__ int hist[NBUCK_MAX];
    __shared__ int base[NBUCK_MAX];
    int tid = threadIdx.x;
    int bstart = blockIdx.x * BINA_CHUNK;
    int bend = min(bstart + BINA_CHUNK, nnz);

    for (int i = tid; i < nbuck; i += BINA_THREADS) hist[i] = 0;
    __syncthreads();
    for (int e = bstart + tid; e < bend; e += BINA_THREADS)
        atomicAdd(&hist[rows[e] >> BUCKET_SHIFT], 1);
    __syncthreads();
    for (int b = tid; b < nbuck; b += BINA_THREADS) {
        int c = hist[b];
        base[b] = (c > 0) ? atomicAdd(&bucketCursor[b], c) : 0;
        hist[b] = 0;   // reuse as local cursor
    }
    __syncthreads();
    for (int e = bstart + tid; e < bend; e += BINA_THREADS) {
        int r = rows[e];
        int b = r >> BUCKET_SHIFT;
        int pos = base[b] + atomicAdd(&hist[b], 1);
        u32 key = ((u32)(r & (ROWS_PER_BUCKET - 1)) << 24) | (u32)cols[e];
        u64 packed = (u64)key | ((u64)__float_as_uint(vals[e]) << 32);
        tmp[pos] = packed;
    }
}

// Pass B2: one block per bucket; per-row hist+scan in LDS -> emits final
// per-row CSR offsets and scatters edges into CSR order (L2-local window).
__global__ void lg_binB2(const int* __restrict__ bucketOffs, const u64* __restrict__ tmp,
                         int* __restrict__ offsets, int2* __restrict__ edges, int n) {
    __shared__ int h[ROWS_PER_BUCKET];
    __shared__ int s[ROWS_PER_BUCKET];
    __shared__ int cur[ROWS_PER_BUCKET];
    int bucket = blockIdx.x;
    int row0 = bucket << BUCKET_SHIFT;
    int tid = threadIdx.x;
    int bstart = bucketOffs[bucket];
    int bend = bucketOffs[bucket + 1];

    h[tid] = 0;
    __syncthreads();
    for (int e = bstart + tid; e < bend; e += 256)
        atomicAdd(&h[(u32)((u32)tmp[e]) >> 24], 1);
    __syncthreads();
    int v = h[tid];
    s[tid] = v;
    __syncthreads();
    #pragma unroll
    for (int off = 1; off < 256; off <<= 1) {
        int x = (tid >= off) ? s[tid - off] : 0;
        __syncthreads();
        s[tid] += x;
        __syncthreads();
    }
    int rowOff = bstart + s[tid] - v;
    int r = row0 + tid;
    if (r < n) offsets[r] = rowOff;
    cur[tid] = rowOff;
    __syncthreads();
    for (int e = bstart + tid; e < bend; e += 256) {
        u64 p = tmp[e];
        u32 key = (u32)p;
        int lr = key >> 24;
        int col = (int)(key & 0xFFFFFFu);
        int pos = atomicAdd(&cur[lr], 1);
        edges[pos] = make_int2(col, (int)(u32)(p >> 32));
    }
}

// ---------------- fallback CSR build ----------------

__global__ void lg_hist(const int* __restrict__ rows, int* __restrict__ counts, int nnz) {
    int e = blockIdx.x * blockDim.x + threadIdx.x;
    if (e >= nnz) return;
    atomicAdd(&counts[rows[e]], 1);
}

__global__ void lg_scan1(const int* __restrict__ counts, int* __restrict__ offsets,
                         int* __restrict__ cursor, int n) {
    const int T = 1024;
    int t = threadIdx.x;
    int chunk = (n + T - 1) / T;
    int start = t * chunk;
    int end = min(start + chunk, n);
    int sum = 0;
    for (int i = start; i < end; ++i) sum += counts[i];
    __shared__ int sdata[T];
    sdata[t] = sum;
    __syncthreads();
    #pragma unroll
    for (int off = 1; off < T; off <<= 1) {
        int v = (t >= off) ? sdata[t - off] : 0;
        __syncthreads();
        sdata[t] += v;
        __syncthreads();
    }
    int offset = sdata[t] - sum;
    for (int i = start; i < end; ++i) {
        int c = counts[i];
        offsets[i] = offset;
        cursor[i] = offset;
        offset += c;
    }
    if (t == T - 1) offsets[n] = sdata[T - 1];
}

__global__ void lg_fill(const int* __restrict__ rows, const int* __restrict__ cols,
                        const float* __restrict__ vals, int* __restrict__ cursor,
                        u64* __restrict__ edges, int nnz) {
    int e = blockIdx.x * blockDim.x + threadIdx.x;
    if (e >= nnz) return;
    int pos = atomicAdd(&cursor[rows[e]], 1);
    u64 packed = (u64)(u32)cols[e] | ((u64)__float_as_uint(vals[e]) << 32);
    edges[pos] = packed;
}

// ---------------- pull SpMM (bf16 gather, fp32 accumulate) ----------------

__global__ void lg_pull_bf16(const int* __restrict__ offs, const int2* __restrict__ edges,
                             const u32* __restrict__ src,
                             u32* __restrict__ nxt, int n) {
    int row = blockIdx.x * (blockDim.x >> 6) + (threadIdx.x >> 6);
    if (row >= n) return;
    int lane = threadIdx.x & 63;
    int sub = lane >> 4;
    int q = lane & 15;

    int beg = offs[row];
    int end = offs[row + 1];
    float4 acc = make_float4(0.f, 0.f, 0.f, 0.f);

    int j = beg + sub;
    for (; j + 4 < end; j += 8) {
        int2 e0 = edges[j];
        int2 e1 = edges[j + 4];
        uint2 g0 = ((const uint2*)(src + (size_t)e0.x * 32))[q];
        uint2 g1 = ((const uint2*)(src + (size_t)e1.x * 32))[q];
        float v0 = __int_as_float(e0.y);
        float v1 = __int_as_float(e1.y);
        acc.x += v0 * bflo(g0.x) + v1 * bflo(g1.x);
        acc.y += v0 * bfhi(g0.x) + v1 * bfhi(g1.x);
        acc.z += v0 * bflo(g0.y) + v1 * bflo(g1.y);
        acc.w += v0 * bfhi(g0.y) + v1 * bfhi(g1.y);
    }
    for (; j < end; j += 4) {
        int2 e = edges[j];
        uint2 g = ((const uint2*)(src + (size_t)e.x * 32))[q];
        float v = __int_as_float(e.y);
        acc.x += v * bflo(g.x);
        acc.y += v * bfhi(g.x);
        acc.z += v * bflo(g.y);
        acc.w += v * bfhi(g.y);
    }

    acc.x += __shfl_xor(acc.x, 16, 64); acc.x += __shfl_xor(acc.x, 32, 64);
    acc.y += __shfl_xor(acc.y, 16, 64); acc.y += __shfl_xor(acc.y, 32, 64);
    acc.z += __shfl_xor(acc.z, 16, 64); acc.z += __shfl_xor(acc.z, 32, 64);
    acc.w += __shfl_xor(acc.w, 16, 64); acc.w += __shfl_xor(acc.w, 32, 64);

    float ss = acc.x * acc.x + acc.y * acc.y + acc.z * acc.z + acc.w * acc.w;
    #pragma unroll
    for (int off = 1; off < 16; off <<= 1) ss += __shfl_xor(ss, off, 64);
    float inv = 1.0f / fmaxf(sqrtf(ss), 1e-12f);

    if (sub == 0) {
        uint2 o = make_uint2(pack_bf16x2(acc.x * inv, acc.y * inv),
                             pack_bf16x2(acc.z * inv, acc.w * inv));
        ((uint2*)(nxt + (size_t)row * 32))[q] = o;
    }
}

// Final pull: layer-3 propagation fused with the 4-layer mean.
// out[row] = (e0_fp32 + e1 + e2 + normalize(gather)) * 0.25
__global__ void lg_pull_final(const int* __restrict__ offs, const int2* __restrict__ edges,
                              const u32* __restrict__ src,      // e2 table (gather source)
                              const float4* __restrict__ user, const float4* __restrict__ item,
                              int nU,
                              const u32* __restrict__ e1b,
                              float4* __restrict__ out, int n) {
    int row = blockIdx.x * (blockDim.x >> 6) + (threadIdx.x >> 6);
    if (row >= n) return;
    int lane = threadIdx.x & 63;
    int sub = lane >> 4;
    int q = lane & 15;

    int beg = offs[row];
    int end = offs[row + 1];
    float4 acc = make_float4(0.f, 0.f, 0.f, 0.f);

    int j = beg + sub;
    for (; j + 4 < end; j += 8) {
        int2 e0 = edges[j];
        int2 e1 = edges[j + 4];
        uint2 g0 = ((const uint2*)(src + (size_t)e0.x * 32))[q];
        uint2 g1 = ((const uint2*)(src + (size_t)e1.x * 32))[q];
        float v0 = __int_as_float(e0.y);
        float v1 = __int_as_float(e1.y);
        acc.x += v0 * bflo(g0.x) + v1 * bflo(g1.x);
        acc.y += v0 * bfhi(g0.x) + v1 * bfhi(g1.x);
        acc.z += v0 * bflo(g0.y) + v1 * bflo(g1.y);
        acc.w += v0 * bfhi(g0.y) + v1 * bfhi(g1.y);
    }
    for (; j < end; j += 4) {
        int2 e = edges[j];
        uint2 g = ((const uint2*)(src + (size_t)e.x * 32))[q];
        float v = __int_as_float(e.y);
        acc.x += v * bflo(g.x);
        acc.y += v * bfhi(g.x);
        acc.z += v * bflo(g.y);
        acc.w += v * bfhi(g.y);
    }

    acc.x += __shfl_xor(acc.x, 16, 64); acc.x += __shfl_xor(acc.x, 32, 64);
    acc.y += __shfl_xor(acc.y, 16, 64); acc.y += __shfl_xor(acc.y, 32, 64);
    acc.z += __shfl_xor(acc.z, 16, 64); acc.z += __shfl_xor(acc.z, 32, 64);
    acc.w += __shfl_xor(acc.w, 16, 64); acc.w += __shfl_xor(acc.w, 32, 64);

    float ss = acc.x * acc.x + acc.y * acc.y + acc.z * acc.z + acc.w * acc.w;
    #pragma unroll
    for (int off = 1; off < 16; off <<= 1) ss += __shfl_xor(ss, off, 64);
    float inv = 1.0f / fmaxf(sqrtf(ss), 1e-12f);

    if (sub == 0) {
        float4 a = (row < nU) ? user[row * 16 + q] : item[(row - nU) * 16 + q];
        uint2 b1 = ((const uint2*)(e1b + (size_t)row * 32))[q];
        uint2 b2 = ((const uint2*)(src + (size_t)row * 32))[q];
        float4 r;
        r.x = (a.x + bflo(b1.x) + bflo(b2.x) + acc.x * inv) * 0.25f;
        r.y = (a.y + bfhi(b1.x) + bfhi(b2.x) + acc.y * inv) * 0.25f;
        r.z = (a.z + bflo(b1.y) + bflo(b2.y) + acc.z * inv) * 0.25f;
        r.w = (a.w + bfhi(b1.y) + bfhi(b2.y) + acc.w * inv) * 0.25f;
        out[(size_t)row * 16 + q] = r;
    }
}

// ---------------- fallback (atomic-scatter fp32 path) ----------------

__global__ void lg_init(const float4* __restrict__ user, const float4* __restrict__ item,
                        float4* __restrict__ cur, float4* __restrict__ sum,
                        int user_vec4, int total_vec4) {
    int i = blockIdx.x * blockDim.x + threadIdx.x;
    if (i >= total_vec4) return;
    float4 v = (i < user_vec4) ? user[i] : item[i - user_vec4];
    cur[i] = v;
    sum[i] = v;
}

__global__ void lg_scatter(const int* __restrict__ rows, const int* __restrict__ cols,
                           const float* __restrict__ vals,
                           const float* __restrict__ cur, float* __restrict__ next,
                           int nnz) {
    int gid = blockIdx.x * blockDim.x + threadIdx.x;
    int e = gid >> 6;
    int d = gid & 63;
    if (e >= nnz) return;
    atomicAdd(&next[rows[e] * D + d], vals[e] * cur[cols[e] * D + d]);
}

__global__ void lg_norm_acc(float* __restrict__ emb, float* __restrict__ sum, int n) {
    int row = blockIdx.x * (blockDim.x >> 6) + (threadIdx.x >> 6);
    int d = threadIdx.x & 63;
    if (row >= n) return;
    int idx = row * D + d;
    float v = emb[idx];
    float ss = v * v;
    #pragma unroll
    for (int off = 32; off > 0; off >>= 1) ss += __shfl_xor(ss, off, 64);
    float out = v / fmaxf(sqrtf(ss), 1e-12f);
    emb[idx] = out;
    sum[idx] += out;
}

__global__ void lg_final(float4* __restrict__ out, int n4) {
    int i = blockIdx.x * blockDim.x + threadIdx.x;
    if (i >= n4) return;
    float4 s = out[i];
    out[i] = make_float4(s.x * 0.25f, s.y * 0.25f, s.z * 0.25f, s.w * 0.25f);
}

// ---------------- launch ----------------

extern "C" void kernel_launch(void* const* d_in, const int* in_sizes, int n_in,
                              void* d_out, int out_size, void* d_ws, size_t ws_size,
                              hipStream_t stream) {
    const float* user = (const float*)d_in[0];
    const float* item = (const float*)d_in[1];
    const float* vals = (const float*)d_in[2];
    const int*   rows = (const int*)d_in[3];
    const int*   cols = (const int*)d_in[4];

    const int nU  = in_sizes[0] / D;
    const int nI  = in_sizes[1] / D;
    const int N   = nU + nI;
    const int nnz = in_sizes[2];

    const size_t embElems = (size_t)N * D;
    const size_t embU32   = (size_t)N * 32;
    const int total4 = (int)(embElems / 4);
    float* out = (float*)d_out;

    // ws layout
    char* p = (char*)d_ws;
    u32* t0  = (u32*)p;           p = align16(p + embU32 * sizeof(u32));
    u32* e1b = (u32*)p;           p = align16(p + embU32 * sizeof(u32));
    u32* e2b = (u32*)p;           p = align16(p + embU32 * sizeof(u32));
    int* counts   = (int*)p;      p = align16(p + (size_t)N * sizeof(int));     // fallback only
    int* offsets  = (int*)p;      p = align16(p + (size_t)(N + 1) * sizeof(int));
    int* cursor   = (int*)p;      p = align16(p + (size_t)N * sizeof(int));     // fallback only
    int* bcounts  = (int*)p;      p = align16(p + NBUCK_MAX * sizeof(int));
    int* bucketOffs = (int*)p;    p = align16(p + (NBUCK_MAX + 1) * sizeof(int));
    int* bucketCursor = (int*)p;  p = align16(p + NBUCK_MAX * sizeof(int));
    u64* edges    = (u64*)p;      p = align16(p + (size_t)nnz * sizeof(u64));
    u64* tmp      = (u64*)p;      p = align16(p + (size_t)nnz * sizeof(u64));
    size_t needBytes = (size_t)(p - (char*)d_ws);
    size_t needNoTmp = needBytes - ((size_t)nnz * sizeof(u64) + 16);

    const int nbuck = (N + ROWS_PER_BUCKET - 1) / ROWS_PER_BUCKET;

    if (ws_size >= needNoTmp) {
        lg_to_bf16<<<(total4 + 255) / 256, 256, 0, stream>>>(
            (const float4*)user, (const float4*)item, (uint2*)t0, nU * D / 4, total4);

        if (nbuck <= NBUCK_MAX && ws_size >= needBytes) {
            hipMemsetAsync(bcounts, 0, (size_t)nbuck * sizeof(int), stream);
            int hb = (nnz + BHIST_CHUNK - 1) / BHIST_CHUNK;
            lg_bhist<<<hb, BHIST_THREADS, 0, stream>>>(rows, bcounts, nnz, nbuck);
            lg_bscan<<<1, 1024, 0, stream>>>(bcounts, bucketOffs, bucketCursor,
                                             offsets + N, nbuck, nnz);
            int ab = (nnz + BINA_CHUNK - 1) / BINA_CHUNK;
            lg_binA<<<ab, BINA_THREADS, 0, stream>>>(rows, cols, vals, bucketCursor,
                                                     tmp, nnz, nbuck);
            lg_binB2<<<nbuck, 256, 0, stream>>>(bucketOffs, tmp, offsets, (int2*)edges, N);
        } else {
            hipMemsetAsync(counts, 0, (size_t)N * sizeof(int), stream);
            int eb = (nnz + 255) / 256;
            lg_hist<<<eb, 256, 0, stream>>>(rows, counts, nnz);
            lg_scan1<<<1, 1024, 0, stream>>>(counts, offsets, cursor, N);
            lg_fill<<<eb, 256, 0, stream>>>(rows, cols, vals, cursor, edges, nnz);
        }

        // ---- layers 1,2 bf16; layer 3 fused with mean ----
        int rb = (N + 3) / 4;
        lg_pull_bf16<<<rb, 256, 0, stream>>>(offsets, (const int2*)edges, t0,  e1b, N);
        lg_pull_bf16<<<rb, 256, 0, stream>>>(offsets, (const int2*)edges, e1b, e2b, N);
        lg_pull_final<<<rb, 256, 0, stream>>>(offsets, (const int2*)edges, e2b,
                                              (const float4*)user, (const float4*)item, nU,
                                              e1b, (float4*)out, N);
    } else {
        // fallback: fp32 atomic scatter
        float* buf0 = (float*)t0;
        float* buf1 = buf0 + embElems;
        float* sum  = out;
        lg_init<<<(total4 + 255) / 256, 256, 0, stream>>>(
            (const float4*)user, (const float4*)item,
            (float4*)buf0, (float4*)sum, nU * D / 4, total4);
        float* cur = buf0;
        float* nxt = buf1;
        for (int layer = 0; layer < 3; ++layer) {
            hipMemsetAsync(nxt, 0, embElems * sizeof(float), stream);
            int totThreads = nnz * 64;
            int blocks = (totThreads + 255) / 256;
            lg_scatter<<<blocks, 256, 0, stream>>>(rows, cols, vals, cur, nxt, nnz);
            lg_norm_acc<<<(N + 3) / 4, 256, 0, stream>>>(nxt, sum, N);
            float* t = cur; cur = nxt; nxt = t;
        }
        lg_final<<<(total4 + 255) / 256, 256, 0, stream>>>((float4*)sum, total4);
    }
}